// Round 9
// baseline (323.323 us; speedup 1.0000x reference)
//
#include <hip/hip_runtime.h>

// GRUObservationCellLogvar — R9: natural-row-order streaming windows.
// N=500000, N_OBS=200000, D=32, H=128, P=4
// out = [ h_updated (500000*128) | losses (200000*32) ] fp32
//
// k_prepack: W -> bf16 B-fragments (ws, 192 KB), per col-group cg:
//            f 0-7 R(k=0..255), 8-15 Z, 16-19 IN(k<128), 20-23 HN(k>=128)
// k_flagpos: obs_pos[i_obs[i]] = i   (after memsetAsync 0xFF -> -1)
// k_win:     block b owns h rows [64b,64b+64):
//            stream window -> LDS (fp32) ; ballot-compact observed rows ;
//            prep losses+A-frags for m slots ; mfma over ceil(m/16) groups
//            (B resident in VGPR) ; GRU epilogue updates window in place ;
//            stream window -> out_h (covers copy + update, all coalesced).

typedef __attribute__((ext_vector_type(8))) short bf16x8;
typedef __attribute__((ext_vector_type(4))) float f32x4;

__device__ inline unsigned short f2bf_rne(float x) {
    union { float f; unsigned int u; } v; v.f = x;
    unsigned int r = (v.u + 0x7fffu + ((v.u >> 16) & 1u)) >> 16;
    return (unsigned short)r;
}
__device__ inline unsigned short f2bf_tr(float x) {
    return (unsigned short)(__float_as_uint(x) >> 16);
}
__device__ inline float fast_sigmoid(float x) {
    return __builtin_amdgcn_rcpf(1.f + __expf(-x));
}
__device__ inline float fast_tanh(float x) {
    const float a = fabsf(x);
    const float t = __expf(-2.f * a);
    const float r = (1.f - t) * __builtin_amdgcn_rcpf(1.f + t);
    return __builtin_copysignf(r, x);
}

// ---- B prepack: 98304 bf16 = 8 cg * 24 frags * 64 lanes * 8 (RNE) ----
__global__ __launch_bounds__(256) void k_prepack(const float* __restrict__ W_ih,
                                                 const float* __restrict__ W_hh,
                                                 unsigned short* __restrict__ B) {
    const int i = blockIdx.x * 256 + threadIdx.x;
    const int w    = i / 12288;
    const int rem  = i - w * 12288;
    const int f    = rem >> 9;
    const int rem2 = rem & 511;
    const int l    = rem2 >> 3;
    const int j    = rem2 & 7;
    const int c    = w * 16 + (l & 15);
    const int ko   = (l >> 4) * 8 + j;
    float val;
    if (f < 8) {
        const int k = f * 32 + ko;
        val = (k < 128) ? W_ih[c * 128 + k] : W_hh[c * 128 + (k - 128)];
    } else if (f < 16) {
        const int k = (f - 8) * 32 + ko;
        val = (k < 128) ? W_ih[(128 + c) * 128 + k] : W_hh[(128 + c) * 128 + (k - 128)];
    } else if (f < 20) {
        const int k = (f - 16) * 32 + ko;
        val = W_ih[(256 + c) * 128 + k];
    } else {
        const int k = (f - 20 + 4) * 32 + ko;
        val = W_hh[(256 + c) * 128 + (k - 128)];
    }
    B[i] = f2bf_rne(val);
}

__global__ __launch_bounds__(256) void k_flagpos(const int* __restrict__ i_obs,
                                                 int* __restrict__ obs_pos, int n) {
    const int i = blockIdx.x * 256 + threadIdx.x;
    if (i < n) obs_pos[i_obs[i]] = i;
}

__global__ __launch_bounds__(512, 4) void k_win(
    const float* __restrict__ h, const float* __restrict__ p,
    const float* __restrict__ X_obs, const float* __restrict__ M_obs,
    const int* __restrict__ obs_pos,
    const float* __restrict__ w_prep, const float* __restrict__ bias_prep,
    const unsigned short* __restrict__ Bpk,
    const float* __restrict__ b_ih, const float* __restrict__ b_hh,
    float* __restrict__ out_h, float* __restrict__ out_losses, int Nh)
{
    __shared__ float hwin[64 * 128];                 // 32 KB fp32 window
    __shared__ unsigned short sA[4 * 8 * 64 * 8];    // 32 KB A-fragments
    __shared__ int sRow[64];                         // slot -> window row
    __shared__ int sPosSlot[64];                     // slot -> obs position
    __shared__ int sPos[64];                         // window row -> obs pos (-1)
    __shared__ int sM[1];

    const int tid   = threadIdx.x;
    const int bid   = blockIdx.x;
    const int r0    = bid * 64;
    const int nrows = (Nh - r0 < 64) ? (Nh - r0) : 64;
    const int nf4   = nrows * 32;

    const int wid  = tid >> 6;
    const int lane = tid & 63;
    const int cw   = wid * 16 + (lane & 15);
    const int d    = tid & 31;

    // ---- resident B fragments (96 VGPR) ----
    bf16x8 breg[24];
    {
        const bf16x8* bsrc = reinterpret_cast<const bf16x8*>(Bpk) + wid * 1536;
        #pragma unroll
        for (int f = 0; f < 24; ++f) breg[f] = bsrc[f * 64 + lane];
    }
    const float bR  = b_ih[cw]       + b_hh[cw];
    const float bZ  = b_ih[128 + cw] + b_hh[128 + cw];
    const float bIN = b_ih[256 + cw];
    const float bHN = b_hh[256 + cw];

    // ---- 1) stream window h -> LDS (coalesced) + obs map ----
    {
        const f32x4* hs = reinterpret_cast<const f32x4*>(h + (size_t)r0 * 128);
        f32x4* hw4 = reinterpret_cast<f32x4*>(hwin);
        #pragma unroll
        for (int pass = 0; pass < 4; ++pass) {
            const int i = pass * 512 + tid;
            if (i < nf4) hw4[i] = hs[i];
        }
        if (tid < 64) sPos[tid] = (tid < nrows) ? obs_pos[r0 + tid] : -1;
    }
    __syncthreads();

    // ---- 2) compact observed rows (wave 0) ----
    if (tid < 64) {
        const int pos = sPos[tid];
        const unsigned long long mask = __ballot(pos >= 0);
        const int slot = __popcll(mask & ((1ull << tid) - 1ull));
        if (pos >= 0) { sRow[slot] = tid; sPosSlot[slot] = pos; }
        if (tid == 0) sM[0] = __popcll(mask);
    }
    __syncthreads();

    const int m = sM[0];

    // ---- 3) prep: losses + A-fragments for slots 0..m-1 ----
    if (m > 0) {
        float wp[16], bp[4];
        #pragma unroll
        for (int t = 0; t < 16; ++t) wp[t] = w_prep[d * 16 + t];
        #pragma unroll
        for (int t = 0; t < 4; ++t) bp[t] = bias_prep[d * 4 + t];

        const int ksA  = d >> 3;                 // gi frag coords (k = 4d..4d+3)
        const int l16A = ((d >> 1) & 3) * 16;
        const int j0A  = (d & 1) * 4;
        const int ksH  = 4 + (d >> 3);           // h frag coords (k = 128+4d..)
        const int l16H = ((d >> 1) & 3) * 16;
        const int j0H  = (d & 1) * 4;

        for (int s = tid >> 5; s < m; s += 16) {
            const int r   = sRow[s];
            const int pos = sPosSlot[s];
            const float mean   = p[(size_t)(r0 + r) * 64 + d];
            const float logvar = p[(size_t)(r0 + r) * 64 + 32 + d];
            const float X  = X_obs[(size_t)pos * 32 + d];
            const float Mم = M_obs[(size_t)pos * 32 + d];
            const float lv      = fminf(fmaxf(logvar, -10.f), 10.f);
            const float inv_sig = __expf(-0.5f * lv);
            const float err     = fminf(fmaxf((X - mean) * inv_sig, -1e6f), 1e6f);
            out_losses[(size_t)pos * 32 + d] =
                0.5f * ((err * err + lv + 1.8378770664093453f) * Mم);
            ushort4 u;
            float g0 = fmaf(X, wp[0], fmaf(mean, wp[4], fmaf(lv, wp[8],  fmaf(err, wp[12], bp[0]))));
            float g1 = fmaf(X, wp[1], fmaf(mean, wp[5], fmaf(lv, wp[9],  fmaf(err, wp[13], bp[1]))));
            float g2 = fmaf(X, wp[2], fmaf(mean, wp[6], fmaf(lv, wp[10], fmaf(err, wp[14], bp[2]))));
            float g3 = fmaf(X, wp[3], fmaf(mean, wp[7], fmaf(lv, wp[11], fmaf(err, wp[15], bp[3]))));
            u.x = f2bf_tr(fmaxf(g0, 0.f) * Mم);
            u.y = f2bf_tr(fmaxf(g1, 0.f) * Mم);
            u.z = f2bf_tr(fmaxf(g2, 0.f) * Mم);
            u.w = f2bf_tr(fmaxf(g3, 0.f) * Mم);
            const int mt  = s >> 4;
            const int r15 = s & 15;
            *reinterpret_cast<ushort4*>(&sA[((mt * 8 + ksA) * 64 + r15 + l16A) * 8 + j0A]) = u;
            // h fragment from the fp32 window
            const f32x4 hv = *reinterpret_cast<const f32x4*>(&hwin[r * 128 + d * 4]);
            ushort4 uh;
            uh.x = f2bf_tr(hv.x); uh.y = f2bf_tr(hv.y); uh.z = f2bf_tr(hv.z); uh.w = f2bf_tr(hv.w);
            *reinterpret_cast<ushort4*>(&sA[((mt * 8 + ksH) * 64 + r15 + l16H) * 8 + j0H]) = uh;
        }
    }
    __syncthreads();

    // ---- 4) MFMA + GRU epilogue (in-place window update) ----
    if (m > 0) {
        const int mtn = (m + 15) >> 4;
        const bf16x8* aptr = reinterpret_cast<const bf16x8*>(sA);
        for (int mt = 0; mt < mtn; ++mt) {
            f32x4 accR = {0.f, 0.f, 0.f, 0.f};
            f32x4 accZ = {0.f, 0.f, 0.f, 0.f};
            f32x4 accIN = {0.f, 0.f, 0.f, 0.f};
            f32x4 accHN = {0.f, 0.f, 0.f, 0.f};
            #pragma unroll
            for (int ks = 0; ks < 8; ++ks) {
                const bf16x8 af = aptr[(mt * 8 + ks) * 64 + lane];
                accR = __builtin_amdgcn_mfma_f32_16x16x32_bf16(af, breg[ks],     accR, 0, 0, 0);
                accZ = __builtin_amdgcn_mfma_f32_16x16x32_bf16(af, breg[8 + ks], accZ, 0, 0, 0);
                if (ks < 4) accIN = __builtin_amdgcn_mfma_f32_16x16x32_bf16(af, breg[16 + ks], accIN, 0, 0, 0);
                else        accHN = __builtin_amdgcn_mfma_f32_16x16x32_bf16(af, breg[16 + ks], accHN, 0, 0, 0);
            }
            const int r15b = (lane >> 4) * 4;
            #pragma unroll
            for (int reg = 0; reg < 4; ++reg) {
                const int s = mt * 16 + r15b + reg;
                if (s < m) {
                    const int r = sRow[s];
                    const float hp  = hwin[r * 128 + cw];      // fp32 h_old
                    const float xr  = accR[reg]  + bR;
                    const float xz  = accZ[reg]  + bZ;
                    const float xin = accIN[reg] + bIN;
                    const float xhn = accHN[reg] + bHN;
                    const float rg = fast_sigmoid(xr);
                    const float zg = fast_sigmoid(xz);
                    const float ng = fast_tanh(fmaf(rg, xhn, xin));
                    hwin[r * 128 + cw] = fmaf(zg, hp - ng, ng);  // col-disjoint
                }
            }
        }
    }
    __syncthreads();

    // ---- 5) stream window -> out_h (coalesced, covers copy + update) ----
    {
        const f32x4* hw4 = reinterpret_cast<const f32x4*>(hwin);
        f32x4* ho = reinterpret_cast<f32x4*>(out_h + (size_t)r0 * 128);
        #pragma unroll
        for (int pass = 0; pass < 4; ++pass) {
            const int i = pass * 512 + tid;
            if (i < nf4) __builtin_nontemporal_store(hw4[i], &ho[i]);
        }
    }
}

extern "C" void kernel_launch(void* const* d_in, const int* in_sizes, int n_in,
                              void* d_out, int out_size, void* d_ws, size_t ws_size,
                              hipStream_t stream) {
    const float* h         = (const float*)d_in[0];
    const float* p         = (const float*)d_in[1];
    const float* X_obs     = (const float*)d_in[2];
    const float* M_obs     = (const float*)d_in[3];
    const int*   i_obs     = (const int*)d_in[4];
    const float* w_prep    = (const float*)d_in[5];
    const float* bias_prep = (const float*)d_in[6];
    const float* W_ih      = (const float*)d_in[7];
    const float* W_hh      = (const float*)d_in[8];
    const float* b_ih      = (const float*)d_in[9];
    const float* b_hh      = (const float*)d_in[10];

    const int Nh   = in_sizes[0] / 128;   // 500000
    const int NOBS = in_sizes[4];         // 200000

    float* out_h      = (float*)d_out;
    float* out_losses = out_h + (size_t)Nh * 128;

    unsigned short* Bpk = (unsigned short*)d_ws;                 // 192 KB
    int* obs_pos = (int*)((char*)d_ws + (256 << 10));            // Nh*4 B

    hipLaunchKernelGGL(k_prepack, dim3(98304 / 256), dim3(256), 0, stream,
                       W_ih, W_hh, Bpk);
    (void)hipMemsetAsync(obs_pos, 0xFF, (size_t)Nh * 4, stream); // -1
    hipLaunchKernelGGL(k_flagpos, dim3((NOBS + 255) / 256), dim3(256), 0, stream,
                       i_obs, obs_pos, NOBS);

    const int grid = (Nh + 63) / 64;      // 7813 windows
    hipLaunchKernelGGL(k_win, dim3(grid), dim3(512), 0, stream,
                       h, p, X_obs, M_obs, obs_pos, w_prep, bias_prep, Bpk,
                       b_ih, b_hh, out_h, out_losses, Nh);
}